// Round 1
// baseline (27.966 us; speedup 1.0000x reference)
//
#include <hip/hip_runtime.h>

#define BROWS 8192
#define TPB   256
#define NTILE (BROWS / TPB)   // 32

// Loss: (1e-4 + sum_ij |A_i - D_i . logp_j|) / B^2
// per-row: logp from 2-class log-softmax; q = clip(one_hot,1e-4,1)*class_w;
// A_i = p.logp - q.log q ; D = p - q.
__global__ __launch_bounds__(TPB) void pair_loss_kernel(
    const float* __restrict__ s,   // [B,2]
    const float* __restrict__ cw,  // [2]
    const int*   __restrict__ t,   // [B]
    float* __restrict__ out)       // [1]
{
    const int tid   = threadIdx.x;
    const int itile = blockIdx.x;
    const int jtile = blockIdx.y;
    const float w0 = cw[0], w1 = cw[1];

    // ---- my i-row stats (registers) ----
    const int i = itile * TPB + tid;
    float2 si = *reinterpret_cast<const float2*>(s + 2 * i);
    float mi   = fmaxf(si.x, si.y);
    float lsei = mi + logf(expf(si.x - mi) + expf(si.y - mi));
    float li0  = si.x - lsei, li1 = si.y - lsei;
    float p0   = expf(li0),   p1  = expf(li1);
    const int ti = t[i];
    float q0 = (ti == 0 ? 1.0f : 1e-4f) * w0;
    float q1 = (ti == 1 ? 1.0f : 1e-4f) * w1;
    float A  = p0 * li0 + p1 * li1 - q0 * logf(q0) - q1 * logf(q1);
    float D0 = p0 - q0, D1 = p1 - q1;

    // ---- j-chunk logp into LDS (each thread computes one j-row) ----
    __shared__ float2 lj[TPB];
    const int j = jtile * TPB + tid;
    float2 sj = *reinterpret_cast<const float2*>(s + 2 * j);
    float mj   = fmaxf(sj.x, sj.y);
    float lsej = mj + logf(expf(sj.x - mj) + expf(sj.y - mj));
    lj[tid] = make_float2(sj.x - lsej, sj.y - lsej);
    __syncthreads();

    // ---- 256 pairs per thread; LDS reads are wave-uniform (broadcast) ----
    float acc = 0.0f;
#pragma unroll 8
    for (int k = 0; k < TPB; ++k) {
        float2 l = lj[k];
        acc += fabsf(A - D0 * l.x - D1 * l.y);
    }

    // ---- wave (64-lane!) then cross-wave reduce ----
    for (int off = 32; off > 0; off >>= 1)
        acc += __shfl_down(acc, off, 64);
    __shared__ float wsum[TPB / 64];
    if ((tid & 63) == 0) wsum[tid >> 6] = acc;
    __syncthreads();
    if (tid == 0) {
        float tot = 0.0f;
#pragma unroll
        for (int w = 0; w < TPB / 64; ++w) tot += wsum[w];
        const float inv = 1.0f / ((float)BROWS * (float)BROWS);
        float contrib = tot * inv;
        if (itile == 0 && jtile == 0) contrib += 1e-4f * inv; // LOSS_INIT
        atomicAdd(out, contrib);
    }
}

extern "C" void kernel_launch(void* const* d_in, const int* in_sizes, int n_in,
                              void* d_out, int out_size, void* d_ws, size_t ws_size,
                              hipStream_t stream) {
    const float* s  = (const float*)d_in[0];
    const float* cw = (const float*)d_in[1];
    const int*   t  = (const int*)d_in[2];
    float* out = (float*)d_out;

    // harness does not re-poison d_out between replays -> zero it every call
    hipMemsetAsync(out, 0, sizeof(float), stream);

    dim3 grid(NTILE, NTILE);  // 32 x 32 blocks of 256x256 pairs
    pair_loss_kernel<<<grid, TPB, 0, stream>>>(s, cw, t, out);
}

// Round 2
// 12.957 us; speedup vs baseline: 2.1583x; 2.1583x over previous
//
#include <hip/hip_runtime.h>

#define BROWS   8192
#define TPB     256
#define NTILE   (BROWS / TPB)     // 32
#define NBLOCKS (NTILE * NTILE)   // 1024

// loss = (1e-4 + sum_ij |A_i - D_i . logp_j|) / B^2   (C = 2)
// A_i = p.logp - q.log q ; D = p - q ; q = clip(onehot,1e-4,1)*class_w

__global__ __launch_bounds__(TPB) void pair_partial_kernel(
    const float* __restrict__ s,        // [B,2]
    const float* __restrict__ cw,       // [2]
    const int*   __restrict__ t,        // [B]
    float* __restrict__ partials)       // [NBLOCKS]
{
    const int tid   = threadIdx.x;
    const int itile = blockIdx.x;
    const int jtile = blockIdx.y;
    const float w0 = cw[0], w1 = cw[1];

    // ---- my i-row stats (registers), fast transcendentals ----
    const int i = itile * TPB + tid;
    float2 si = *reinterpret_cast<const float2*>(s + 2 * i);
    float mi  = fmaxf(si.x, si.y);
    float ei0 = __expf(si.x - mi), ei1 = __expf(si.y - mi);
    float lsei = mi + __logf(ei0 + ei1);
    float li0 = si.x - lsei, li1 = si.y - lsei;
    float p0  = __expf(li0),  p1  = __expf(li1);
    const int ti = t[i];
    float q0 = (ti == 0 ? 1.0f : 1e-4f) * w0;
    float q1 = (ti == 1 ? 1.0f : 1e-4f) * w1;
    float A  = p0 * li0 + p1 * li1 - q0 * __logf(q0) - q1 * __logf(q1);
    float D0 = p0 - q0, D1 = p1 - q1;

    // ---- j-chunk logp into LDS, SoA + 16B aligned for b128 broadcasts ----
    __shared__ __align__(16) float ljx[TPB];
    __shared__ __align__(16) float ljy[TPB];
    const int j = jtile * TPB + tid;
    float2 sj = *reinterpret_cast<const float2*>(s + 2 * j);
    float mj  = fmaxf(sj.x, sj.y);
    float ej0 = __expf(sj.x - mj), ej1 = __expf(sj.y - mj);
    float lsej = mj + __logf(ej0 + ej1);
    ljx[tid] = sj.x - lsej;
    ljy[tid] = sj.y - lsej;
    __syncthreads();

    // ---- 256 pairs/thread; uniform-address b128 reads (broadcast, 0 conflicts)
    float acc = 0.0f;
#pragma unroll
    for (int k = 0; k < TPB; k += 4) {
        float4 x = *reinterpret_cast<const float4*>(&ljx[k]);
        float4 y = *reinterpret_cast<const float4*>(&ljy[k]);
        acc += fabsf(A - D0 * x.x - D1 * y.x);
        acc += fabsf(A - D0 * x.y - D1 * y.y);
        acc += fabsf(A - D0 * x.z - D1 * y.z);
        acc += fabsf(A - D0 * x.w - D1 * y.w);
    }

    // ---- wave (64-lane) + cross-wave reduce, one global write per block ----
    for (int off = 32; off > 0; off >>= 1)
        acc += __shfl_down(acc, off, 64);
    __shared__ float wsum[TPB / 64];
    if ((tid & 63) == 0) wsum[tid >> 6] = acc;
    __syncthreads();
    if (tid == 0) {
        float tot = wsum[0] + wsum[1] + wsum[2] + wsum[3];
        partials[blockIdx.y * NTILE + blockIdx.x] = tot;   // unscaled
    }
}

__global__ __launch_bounds__(TPB) void final_reduce_kernel(
    const float* __restrict__ partials, float* __restrict__ out)
{
    const int tid = threadIdx.x;
    float a = partials[tid] + partials[tid + 256] +
              partials[tid + 512] + partials[tid + 768];
    for (int off = 32; off > 0; off >>= 1)
        a += __shfl_down(a, off, 64);
    __shared__ float wsum[TPB / 64];
    if ((tid & 63) == 0) wsum[tid >> 6] = a;
    __syncthreads();
    if (tid == 0) {
        float tot = wsum[0] + wsum[1] + wsum[2] + wsum[3];
        const float inv = 1.0f / ((float)BROWS * (float)BROWS);
        out[0] = (1e-4f + tot) * inv;
    }
}

extern "C" void kernel_launch(void* const* d_in, const int* in_sizes, int n_in,
                              void* d_out, int out_size, void* d_ws, size_t ws_size,
                              hipStream_t stream) {
    const float* s  = (const float*)d_in[0];
    const float* cw = (const float*)d_in[1];
    const int*   t  = (const int*)d_in[2];
    float* out      = (float*)d_out;
    float* partials = (float*)d_ws;   // NBLOCKS floats, fully overwritten each call

    dim3 grid(NTILE, NTILE);
    pair_partial_kernel<<<grid, TPB, 0, stream>>>(s, cw, t, partials);
    final_reduce_kernel<<<1, TPB, 0, stream>>>(partials, out);
}